// Round 3
// baseline (464.968 us; speedup 1.0000x reference)
//
#include <hip/hip_runtime.h>

#define B_ROWS 65536
#define D_DIM  1024
#define NC     120   // 100 expert units + 2*10 gate logits
#define MBLK   64    // rows per workgroup
#define CSTR   121   // LDS C stride in floats (odd -> conflict-free epilogue)

typedef __attribute__((ext_vector_type(4))) float f32x4;
typedef __attribute__((ext_vector_type(8))) short bf16x8;

// Module-scope scratch for packed weights (256 KB bf16, B^T layout, plain
// row-major: g_wt[c][d], c=0..127, cols 120..127 zero). L2-resident during
// mmoe_main (256 KB << 4 MiB per-XCD L2), so B fragments are loaded straight
// from global into registers -- no LDS staging, no barriers in the main loop.
__device__ __attribute__((aligned(16))) short g_wt[128 * D_DIM];

__device__ __forceinline__ unsigned short f2bf(float f) {
  union { float f; unsigned u; } v; v.f = f;
  unsigned r = v.u + 0x7FFFu + ((v.u >> 16) & 1u);  // RNE
  return (unsigned short)(r >> 16);
}

__device__ __forceinline__ bf16x8 cvt8(float4 p, float4 q) {
  bf16x8 r;
  r[0] = (short)f2bf(p.x); r[1] = (short)f2bf(p.y);
  r[2] = (short)f2bf(p.z); r[3] = (short)f2bf(p.w);
  r[4] = (short)f2bf(q.x); r[5] = (short)f2bf(q.y);
  r[6] = (short)f2bf(q.z); r[7] = (short)f2bf(q.w);
  return r;
}

// Pack expert_w [E=10][D=1024][U=10] and gate_w [T=2][D=1024][E=10] into
// g_wt[c][d] (no swizzle needed anymore: B is consumed via register loads).
__global__ __launch_bounds__(256) void pack_w(const float* __restrict__ ew,
                                              const float* __restrict__ gw) {
  int idx = blockIdx.x * 256 + threadIdx.x;   // 128*1024 = 131072 total
  int c = idx >> 10, d = idx & 1023;
  float v = 0.f;
  if (c < 100) {
    int e = c / 10, u = c % 10;
    v = ew[(e * D_DIM + d) * 10 + u];
  } else if (c < NC) {
    int q = c - 100; int t = q / 10, e = q % 10;
    v = gw[(t * D_DIM + d) * 10 + e];
  }
  g_wt[c * D_DIM + d] = (short)f2bf(v);
}

__global__ __launch_bounds__(256) void mmoe_main(
    const float* __restrict__ x,
    const float* __restrict__ eb, const float* __restrict__ gb,
    const float* __restrict__ ctr_w, const float* __restrict__ ctr_b,
    const float* __restrict__ cvr_w, const float* __restrict__ cvr_b,
    float* __restrict__ out) {
  __shared__ float Cs[MBLK * CSTR];           // 30976 B, epilogue only
  const int tid  = threadIdx.x;
  const int wave = tid >> 6, lane = tid & 63;
  const int lhi  = lane >> 4, llo = lane & 15;
  const int m0   = blockIdx.x * MBLK;

  // A fragment source: row = m0 + wave*16 + llo, k phase = lhi*8
  // (MFMA A layout: row=llo, k=lhi*8+j -> 8 contiguous floats per lane)
  const float* ax = x + (size_t)(m0 + wave * 16 + llo) * D_DIM + lhi * 8;

  // B fragment sources: col = ct*16 + llo, k phase = lhi*8
  // -> 16 contiguous bytes per lane, straight from L2-resident g_wt.
  const short* bp[8];
  #pragma unroll
  for (int ct = 0; ct < 8; ++ct)
    bp[ct] = g_wt + (ct * 16 + llo) * D_DIM + lhi * 8;

  f32x4 acc[8];
  #pragma unroll
  for (int i = 0; i < 8; ++i) acc[i] = (f32x4){0.f, 0.f, 0.f, 0.f};

  // Barrier-free main loop: 4 rolled outer iters x 4 unrolled chunks.
  // All per-load offsets are compile-time immediates; pointers bump by
  // 256 elements per outer iter. Accumulation order identical to the
  // previous (passing) kernel: per chunk, ks=0 over 8 cols then ks=32.
  for (int cc = 0; cc < 4; ++cc) {
    #pragma unroll
    for (int q = 0; q < 4; ++q) {
      const int k0 = q * 64;
      const float4 A0 = *reinterpret_cast<const float4*>(ax + k0);
      const float4 A1 = *reinterpret_cast<const float4*>(ax + k0 + 4);
      const float4 A2 = *reinterpret_cast<const float4*>(ax + k0 + 32);
      const float4 A3 = *reinterpret_cast<const float4*>(ax + k0 + 36);
      const bf16x8 af0 = cvt8(A0, A1);
      const bf16x8 af1 = cvt8(A2, A3);
      #pragma unroll
      for (int ct = 0; ct < 8; ++ct) {
        const bf16x8 bb = *reinterpret_cast<const bf16x8*>(bp[ct] + k0);
        acc[ct] = __builtin_amdgcn_mfma_f32_16x16x32_bf16(af0, bb, acc[ct], 0, 0, 0);
      }
      #pragma unroll
      for (int ct = 0; ct < 8; ++ct) {
        const bf16x8 bb = *reinterpret_cast<const bf16x8*>(bp[ct] + k0 + 32);
        acc[ct] = __builtin_amdgcn_mfma_f32_16x16x32_bf16(af1, bb, acc[ct], 0, 0, 0);
      }
    }
    ax += 256;
    #pragma unroll
    for (int ct = 0; ct < 8; ++ct) bp[ct] += 256;
  }

  // scatter C frags -> LDS rows (C/D layout: col=lane&15, row=quad*4+reg)
  #pragma unroll
  for (int ct = 0; ct < 8; ++ct) {
    const int col = ct * 16 + llo;
    if (col < NC) {
      #pragma unroll
      for (int r = 0; r < 4; ++r)
        Cs[(wave * 16 + lhi * 4 + r) * CSTR + col] = acc[ct][r];
    }
  }
  __syncthreads();

  // epilogue: 128 threads = 64 rows x 2 tasks (wave-uniform task select)
  if (tid < 2 * MBLK) {
    const int task = tid >> 6, row = tid & 63;
    const float* crow = &Cs[row * CSTR];
    const float* wv = task ? cvr_w : ctr_w;
    const float  bv = task ? cvr_b[0] : ctr_b[0];
    float w[10];
    #pragma unroll
    for (int u = 0; u < 10; ++u) w[u] = wv[u];
    // s[e] = sum_u relu(expert[e,u]) * w[u]
    float s[10];
    #pragma unroll
    for (int e = 0; e < 10; ++e) {
      float a = 0.f;
      #pragma unroll
      for (int u = 0; u < 10; ++u) {
        float v = fmaxf(crow[e * 10 + u] + eb[e * 10 + u], 0.f);
        a = fmaf(v, w[u], a);
      }
      s[e] = a;
    }
    // softmax over gate logits, combine, sigmoid
    float gl[10], mx = -1e30f;
    #pragma unroll
    for (int e = 0; e < 10; ++e) {
      gl[e] = crow[100 + task * 10 + e] + gb[task * 10 + e];
      mx = fmaxf(mx, gl[e]);
    }
    float den = 0.f, num = 0.f;
    #pragma unroll
    for (int e = 0; e < 10; ++e) {
      float p = __expf(gl[e] - mx);
      den += p; num = fmaf(p, s[e], num);
    }
    float z = num / den + bv;
    out[task * B_ROWS + m0 + row] = 1.f / (1.f + __expf(-z));
  }
}

extern "C" void kernel_launch(void* const* d_in, const int* in_sizes, int n_in,
                              void* d_out, int out_size, void* d_ws, size_t ws_size,
                              hipStream_t stream) {
  const float* x     = (const float*)d_in[0];
  // d_in[1] show_index, d_in[2] st: unused by the reference math
  const float* ew    = (const float*)d_in[3];
  const float* eb    = (const float*)d_in[4];
  const float* gw    = (const float*)d_in[5];
  const float* gb    = (const float*)d_in[6];
  const float* ctr_w = (const float*)d_in[7];
  const float* ctr_b = (const float*)d_in[8];
  const float* cvr_w = (const float*)d_in[9];
  const float* cvr_b = (const float*)d_in[10];
  float* out = (float*)d_out;
  (void)d_ws; (void)ws_size;  // workspace unused (poison fills proven unconditional)

  pack_w<<<512, 256, 0, stream>>>(ew, gw);
  mmoe_main<<<B_ROWS / MBLK, 256, 0, stream>>>(x, eb, gb, ctr_w, ctr_b,
                                               cvr_w, cvr_b, out);
}

// Round 6
// 391.103 us; speedup vs baseline: 1.1889x; 1.1889x over previous
//
#include <hip/hip_runtime.h>

#define B_ROWS 65536
#define D_DIM  1024
#define NC     120   // 100 expert units + 2*10 gate logits
#define MBLK   64    // rows per workgroup
#define BK     64    // K chunk
#define CSTR   121   // LDS C stride in floats (odd -> conflict-free epilogue)

typedef __attribute__((ext_vector_type(4))) float f32x4;
typedef __attribute__((ext_vector_type(8))) short bf16x8;

// Module-scope scratch for packed weights (256 KB). Re-packed every launch
// before mmoe_main reads it (same stream) -> no stale-state dependence.
__device__ __attribute__((aligned(16))) short g_wt[128 * D_DIM];

__device__ __forceinline__ unsigned short f2bf(float f) {
  union { float f; unsigned u; } v; v.f = f;
  unsigned r = v.u + 0x7FFFu + ((v.u >> 16) & 1u);  // RNE
  return (unsigned short)(r >> 16);
}

__device__ __forceinline__ bf16x8 cvt8(float4 p, float4 q) {
  bf16x8 r;
  r[0] = (short)f2bf(p.x); r[1] = (short)f2bf(p.y);
  r[2] = (short)f2bf(p.z); r[3] = (short)f2bf(p.w);
  r[4] = (short)f2bf(q.x); r[5] = (short)f2bf(q.y);
  r[6] = (short)f2bf(q.z); r[7] = (short)f2bf(q.w);
  return r;
}

// Pack expert_w [E=10][D=1024][U=10] and gate_w [T=2][D=1024][E=10] into
// g_wt[c][d] bf16 (c = B^T col, 0..127; cols 120..127 = 0), PRE-SWIZZLED:
// g_wt[c][d ^ ((c&7)<<3)] = W[c][d], so a linear global_load_lds dest + the
// same XOR on the ds_read address gives conflict-free LDS banking.
__global__ __launch_bounds__(256) void pack_w(const float* __restrict__ ew,
                                              const float* __restrict__ gw) {
  int idx = blockIdx.x * 256 + threadIdx.x;   // 128*1024 = 131072 total
  int c = idx >> 10, d = idx & 1023;
  float v = 0.f;
  if (c < 100) {
    int e = c / 10, u = c % 10;
    v = ew[(e * D_DIM + d) * 10 + u];
  } else if (c < NC) {
    int q = c - 100; int t = q / 10, e = q % 10;
    v = gw[(t * D_DIM + d) * 10 + e];
  }
  g_wt[c * D_DIM + (d ^ ((c & 7) << 3))] = (short)f2bf(v);
}

union __align__(16) Smem {
  struct { short B0[128 * 64]; short B1[128 * 64]; } s;  // 2 x 16 KiB
  float C[MBLK * CSTR];                                  // 30976 B
};

typedef const __attribute__((address_space(1))) void as1_cvoid;
typedef __attribute__((address_space(3))) void as3_void;

__device__ __forceinline__ void gload_lds16(const void* g, void* l) {
  // async global->LDS, 16B per lane; HW dest = wave-uniform base + lane*16
  __builtin_amdgcn_global_load_lds((as1_cvoid*)g, (as3_void*)l, 16, 0, 0);
}

__global__ __launch_bounds__(256, 4) void mmoe_main(
    const float* __restrict__ x,
    const float* __restrict__ eb, const float* __restrict__ gb,
    const float* __restrict__ ctr_w, const float* __restrict__ ctr_b,
    const float* __restrict__ cvr_w, const float* __restrict__ cvr_b,
    float* __restrict__ out) {
  __shared__ Smem sm;
  const int tid  = threadIdx.x;
  const int wave = tid >> 6, lane = tid & 63;
  const int lhi  = lane >> 4, llo = lane & 15;
  const int m0   = blockIdx.x * MBLK;
  const int bswz = (llo & 7) << 3;   // read-side XOR (shorts)

  // A fragment source: row = m0 + wave*16 + llo, k phase = lhi*8
  const float* ax = x + (size_t)(m0 + wave * 16 + llo) * D_DIM + lhi * 8;

  // B staging: per issue j, col c=(wave*4+j)*8 + lane/8, 16B at k-offset (lane&7)*8
  const short* bsrc = g_wt + (lane >> 3) * D_DIM + (lane & 7) * 8;
  short* const b0p = sm.s.B0 + wave * 2048 + lane * 8;
  short* const b1p = sm.s.B1 + wave * 2048 + lane * 8;

  f32x4 acc[8];
  #pragma unroll
  for (int i = 0; i < 8; ++i) acc[i] = (f32x4){0.f, 0.f, 0.f, 0.f};
  float4 a0[4], a1[4];

// STAGE issues exactly 4 global_load_lds (vmcnt entries); the trailing
// sched_barrier(0) PINS these before any subsequently-issued VMEM op, so
// the per-wave VMEM FIFO order is provably [stage x4, A x4] at WAITBAR.
// (Round-4 failure: without the fence the compiler interleaved A-loads
// with stage-loads and vmcnt(4) left a stage-load in flight across the
// barrier -> uninitialized LDS -> NaN.)
#define STAGE0(K0) do { _Pragma("unroll") \
    for (int j = 0; j < 4; ++j) \
      gload_lds16(bsrc + (wave * 4 + j) * 8 * D_DIM + (K0), b0p + j * 512); \
    __builtin_amdgcn_sched_barrier(0); \
  } while (0)
#define STAGE1(K0) do { _Pragma("unroll") \
    for (int j = 0; j < 4; ++j) \
      gload_lds16(bsrc + (wave * 4 + j) * 8 * D_DIM + (K0), b1p + j * 512); \
    __builtin_amdgcn_sched_barrier(0); \
  } while (0)
#define LOADA(AR, K0) do { \
    AR[0] = *reinterpret_cast<const float4*>(ax + (K0)); \
    AR[1] = *reinterpret_cast<const float4*>(ax + (K0) + 4); \
    AR[2] = *reinterpret_cast<const float4*>(ax + (K0) + 32); \
    AR[3] = *reinterpret_cast<const float4*>(ax + (K0) + 36); \
  } while (0)
#define COMPUTE(BUF, AR) do { \
    const bf16x8 af0 = cvt8(AR[0], AR[1]); \
    const bf16x8 af1 = cvt8(AR[2], AR[3]); \
    _Pragma("unroll") \
    for (int ct = 0; ct < 8; ++ct) { \
      const bf16x8 b = *reinterpret_cast<const bf16x8*>( \
          (BUF) + (ct * 16 + llo) * 64 + ((lhi * 8) ^ bswz)); \
      acc[ct] = __builtin_amdgcn_mfma_f32_16x16x32_bf16(af0, b, acc[ct], 0, 0, 0); \
    } \
    _Pragma("unroll") \
    for (int ct = 0; ct < 8; ++ct) { \
      const bf16x8 b = *reinterpret_cast<const bf16x8*>( \
          (BUF) + (ct * 16 + llo) * 64 + ((32 + lhi * 8) ^ bswz)); \
      acc[ct] = __builtin_amdgcn_mfma_f32_16x16x32_bf16(af1, b, acc[ct], 0, 0, 0); \
    } \
  } while (0)

// Counted-vmcnt barrier (T4): per-wave VMEM FIFO here is [stage(next) x4,
// A(next) x4] (order pinned by STAGE's sched_barrier). vmcnt(4) retires the
// 4 stage entries (this wave's share of the next buffer is in LDS) while
// the 4 HBM A-loads stay in flight ACROSS the barrier. lgkmcnt(0) retires
// this chunk's ds_reads (closes the WAR window on the buffer the stage
// after next will overwrite). sched_barrier(0) after s_barrier pins next
// chunk's ds_reads below the barrier.
#define WAITBAR() do { \
    asm volatile("s_waitcnt vmcnt(4) lgkmcnt(0)" ::: "memory"); \
    __builtin_amdgcn_s_barrier(); \
    __builtin_amdgcn_sched_barrier(0); \
  } while (0)

  // prologue: chunk 0  (FIFO = [stage0 x4, A0 x4] -> vmcnt(4) retires stage0)
  STAGE0(0);
  LOADA(a0, 0);
  WAITBAR();

  #pragma unroll
  for (int tt = 0; tt < 8; ++tt) {
    const int t = 2 * tt;
    // even chunk t: prefetch t+1 (B->B1, A->regs), compute on (B0, a0)
    STAGE1((t + 1) * BK);
    LOADA(a1, (t + 1) * BK);
    COMPUTE(sm.s.B0, a0);
    WAITBAR();
    // odd chunk t+1: prefetch t+2, compute on (B1, a1)
    if (tt < 7) {
      STAGE0((t + 2) * BK);
      LOADA(a0, (t + 2) * BK);
      COMPUTE(sm.s.B1, a1);
      WAITBAR();
    } else {
      COMPUTE(sm.s.B1, a1);
    }
  }
  __syncthreads();   // full drain before LDS reuse as C

  // scatter C frags -> LDS rows (C/D layout: col=lane&15, row=quad*4+reg)
  #pragma unroll
  for (int ct = 0; ct < 8; ++ct) {
    const int col = ct * 16 + llo;
    if (col < NC) {
      #pragma unroll
      for (int r = 0; r < 4; ++r)
        sm.C[(wave * 16 + lhi * 4 + r) * CSTR + col] = acc[ct][r];
    }
  }
  __syncthreads();

  // epilogue: 128 threads = 64 rows x 2 tasks (wave-uniform task select)
  if (tid < 2 * MBLK) {
    const int task = tid >> 6, row = tid & 63;
    const float* crow = &sm.C[row * CSTR];
    const float* wv = task ? cvr_w : ctr_w;
    const float  bv = task ? cvr_b[0] : ctr_b[0];
    float w[10];
    #pragma unroll
    for (int u = 0; u < 10; ++u) w[u] = wv[u];
    // s[e] = sum_u relu(expert[e,u]) * w[u]
    float s[10];
    #pragma unroll
    for (int e = 0; e < 10; ++e) {
      float a = 0.f;
      #pragma unroll
      for (int u = 0; u < 10; ++u) {
        float v = fmaxf(crow[e * 10 + u] + eb[e * 10 + u], 0.f);
        a = fmaf(v, w[u], a);
      }
      s[e] = a;
    }
    // softmax over gate logits, combine, sigmoid
    float gl[10], mx = -1e30f;
    #pragma unroll
    for (int e = 0; e < 10; ++e) {
      gl[e] = crow[100 + task * 10 + e] + gb[task * 10 + e];
      mx = fmaxf(mx, gl[e]);
    }
    float den = 0.f, num = 0.f;
    #pragma unroll
    for (int e = 0; e < 10; ++e) {
      float p = __expf(gl[e] - mx);
      den += p; num = fmaf(p, s[e], num);
    }
    float z = num / den + bv;
    out[task * B_ROWS + m0 + row] = 1.f / (1.f + __expf(-z));
  }
}

extern "C" void kernel_launch(void* const* d_in, const int* in_sizes, int n_in,
                              void* d_out, int out_size, void* d_ws, size_t ws_size,
                              hipStream_t stream) {
  const float* x     = (const float*)d_in[0];
  // d_in[1] show_index, d_in[2] st: unused by the reference math
  const float* ew    = (const float*)d_in[3];
  const float* eb    = (const float*)d_in[4];
  const float* gw    = (const float*)d_in[5];
  const float* gb    = (const float*)d_in[6];
  const float* ctr_w = (const float*)d_in[7];
  const float* ctr_b = (const float*)d_in[8];
  const float* cvr_w = (const float*)d_in[9];
  const float* cvr_b = (const float*)d_in[10];
  float* out = (float*)d_out;
  (void)d_ws; (void)ws_size;  // workspace unused (poison fills proven unconditional)

  pack_w<<<512, 256, 0, stream>>>(ew, gw);
  mmoe_main<<<B_ROWS / MBLK, 256, 0, stream>>>(x, eb, gb, ctr_w, ctr_b,
                                               cvr_w, cvr_b, out);
}